// Round 1
// 495.191 us; speedup vs baseline: 1.0771x; 1.0771x over previous
//
#include <hip/hip_runtime.h>

#define B_ 8
#define L_ 128
#define D_ 512
#define H_ 8

__device__ __forceinline__ float leaky(float v) { return fmaxf(v, 0.2f * v); }

// ---------------------------------------------------------------------------
// K1: Wr_eff[k][h] = sum_d W_relation[k][h*64+d] * w_rel[h][d]   (512 x 8 fp32)
// ---------------------------------------------------------------------------
__global__ __launch_bounds__(256) void k_wreff(const float* __restrict__ Wrel,
                                               const float* __restrict__ wrel,
                                               float* __restrict__ wr_eff) {
    int t = blockIdx.x * 256 + threadIdx.x;   // 0..4095
    int k = t >> 3, h = t & 7;
    const float4* a = (const float4*)(Wrel + k * 512 + h * 64);
    const float4* b = (const float4*)(wrel + h * 64);
    float acc = 0.f;
#pragma unroll
    for (int q = 0; q < 16; q++) {
        float4 av = a[q], bv = b[q];
        acc += av.x * bv.x + av.y * bv.y + av.z * bv.z + av.w * bv.w;
    }
    wr_eff[k * 8 + h] = acc;
}

// ---------------------------------------------------------------------------
// K2: one launch, two block families (co-scheduled so the small value GEMM
// hides inside the srel HBM stream):
//   blocks 0..2047   : s_rel[b][h][i][j] = leaky(rel[b,i,j,:] . Wr_eff[:,h])
//   blocks 2048..2303: value_t GEMM + e_src/e_tgt
// Change vs prev: each wave owns 16 CONTIGUOUS rows (row = wave*16+it) so the
// 8 per-row 4-B s_rel stores fill complete 64-B lines per (b,h) over the 16
// iterations (previously stride-8192 rows spread each line over 4 blocks /
// multiple XCDs -> partial-line merge traffic at L3).
// ---------------------------------------------------------------------------
__global__ __launch_bounds__(256) void k_srel_value(
        const float* __restrict__ rel, const float* __restrict__ wr_eff,
        const float* __restrict__ inp, const float* __restrict__ Wv,
        const float* __restrict__ wsrc, const float* __restrict__ wtgt,
        float* __restrict__ s_rel, float* __restrict__ value_t,
        float* __restrict__ e_src, float* __restrict__ e_tgt) {
    __shared__ float xs[4][512];
    const int t = threadIdx.x;

    if (blockIdx.x < 2048) {
        // ---------------- srel ----------------
        const int lane = t & 63;
        const int wave = (blockIdx.x * 256 + t) >> 6;   // 0..8191

        float wrl[64];   // wrl[kk*8+h] = wr_eff[(lane*8+kk)*8+h]
        {
            const float4* wp = (const float4*)(wr_eff + lane * 64);
#pragma unroll
            for (int q = 0; q < 16; q++) {
                float4 v = wp[q];
                wrl[q * 4 + 0] = v.x; wrl[q * 4 + 1] = v.y;
                wrl[q * 4 + 2] = v.z; wrl[q * 4 + 3] = v.w;
            }
        }

        const bool hi32 = (lane & 32) != 0;
        const bool hi16 = (lane & 16) != 0;
        const bool hi8  = (lane & 8) != 0;
        const int  hsel = (lane >> 3) & 7;

#pragma unroll 2
        for (int it = 0; it < 16; ++it) {
            int row = wave * 16 + it;                  // contiguous rows per wave
            const float4* rp = (const float4*)(rel + (size_t)row * 512 + lane * 8);
            float4 u0 = rp[0];
            float4 u1 = rp[1];
            float x[8];
            x[0] = u0.x; x[1] = u0.y; x[2] = u0.z; x[3] = u0.w;
            x[4] = u1.x; x[5] = u1.y; x[6] = u1.z; x[7] = u1.w;
            float acc[8] = {0.f,0.f,0.f,0.f,0.f,0.f,0.f,0.f};
#pragma unroll
            for (int kk = 0; kk < 8; kk++)
#pragma unroll
                for (int h = 0; h < 8; h++)
                    acc[h] = fmaf(x[kk], wrl[kk * 8 + h], acc[h]);

            float a4[4];
#pragma unroll
            for (int hh = 0; hh < 4; hh++) {
                float send = hi32 ? acc[hh] : acc[hh + 4];
                float recv = __shfl_xor(send, 32, 64);
                float own  = hi32 ? acc[hh + 4] : acc[hh];
                a4[hh] = own + recv;
            }
            float a2[2];
#pragma unroll
            for (int hh = 0; hh < 2; hh++) {
                float send = hi16 ? a4[hh] : a4[hh + 2];
                float recv = __shfl_xor(send, 16, 64);
                float own  = hi16 ? a4[hh + 2] : a4[hh];
                a2[hh] = own + recv;
            }
            float send = hi8 ? a2[0] : a2[1];
            float recv = __shfl_xor(send, 8, 64);
            float a1 = (hi8 ? a2[1] : a2[0]) + recv;
            a1 += __shfl_xor(a1, 4, 64);
            a1 += __shfl_xor(a1, 2, 64);
            a1 += __shfl_xor(a1, 1, 64);

            if ((lane & 7) == 0) {
                float v = leaky(a1);
                int b = row >> 14, rem = row & 16383;
                s_rel[(((size_t)(b * 8 + hsel)) << 14) + rem] = v;
            }
        }
        return;
    }

    // ---------------- value GEMM ----------------
    const int row0 = (blockIdx.x - 2048) * 4;      // flat b*128+l
    {
        int r = t >> 6, seg = t & 63;
        const float4* ip = (const float4*)(inp + (size_t)(row0 + r) * 512 + seg * 8);
        float4 a = ip[0], bq = ip[1];
        *(float4*)&xs[r][seg * 8]     = a;
        *(float4*)&xs[r][seg * 8 + 4] = bq;
    }
    __syncthreads();
    const int c0 = t * 2;
    float acc[4][2] = {};
    for (int k0 = 0; k0 < 512; k0 += 4) {
        float4 xr[4];
#pragma unroll
        for (int r = 0; r < 4; r++) xr[r] = *(const float4*)&xs[r][k0];
#define VSTEP(COMP, I)                                                          \
        {                                                                       \
            float2 wv = *(const float2*)(Wv + (size_t)(k0 + I) * 512 + c0);     \
            _Pragma("unroll")                                                   \
            for (int r = 0; r < 4; r++) {                                       \
                acc[r][0] = fmaf(xr[r].COMP, wv.x, acc[r][0]);                  \
                acc[r][1] = fmaf(xr[r].COMP, wv.y, acc[r][1]);                  \
            }                                                                   \
        }
        VSTEP(x, 0) VSTEP(y, 1) VSTEP(z, 2) VSTEP(w, 3)
#undef VSTEP
    }
    const int h = t >> 5;
    const int d0 = c0 & 63;
    const int b = row0 >> 7, l0 = row0 & 127;
    {
        float4 v0 = make_float4(acc[0][0], acc[1][0], acc[2][0], acc[3][0]);
        float4 v1 = make_float4(acc[0][1], acc[1][1], acc[2][1], acc[3][1]);
        *(float4*)&value_t[((size_t)((b * 8 + h) * 64 + d0)) * 128 + l0] = v0;
        *(float4*)&value_t[((size_t)((b * 8 + h) * 64 + d0 + 1)) * 128 + l0] = v1;
    }
    float ws0 = wsrc[c0], ws1 = wsrc[c0 + 1];
    float wt0 = wtgt[c0], wt1 = wtgt[c0 + 1];
    float es[4], et[4];
#pragma unroll
    for (int r = 0; r < 4; r++) {
        es[r] = acc[r][0] * ws0 + acc[r][1] * ws1;
        et[r] = acc[r][0] * wt0 + acc[r][1] * wt1;
    }
#pragma unroll
    for (int off = 16; off >= 1; off >>= 1)
#pragma unroll
        for (int r = 0; r < 4; r++) {
            es[r] += __shfl_xor(es[r], off, 64);
            et[r] += __shfl_xor(et[r], off, 64);
        }
    if ((t & 31) == 0) {
#pragma unroll
        for (int r = 0; r < 4; r++) {
            e_src[(b * 8 + h) * 128 + l0 + r] = es[r];
            e_tgt[(b * 8 + h) * 128 + l0 + r] = et[r];
        }
    }
}

// ---------------------------------------------------------------------------
// K3 v2: 512 threads / 8 waves per block (was 256/4; fixes 1-wave/SIMD
// occupancy). Wave w = (row r = w>>1, head-half hh = w&1): each wave does 4
// heads instead of 8 (halves the serial per-head softmax/AV chain). Final
// GEMM is split-K: wave-group g=0 does K 0..511 (xv half), g=1 does K
// 512..1023 (xr half); g=1 writes partials to LDS (aliasing the dead lav/lar
// buffer), g=0 adds + bias + residual + store.
// s_rel aliases out_ar (same-thread read-then-write per head).
// ---------------------------------------------------------------------------
__global__ __launch_bounds__(512) void k_attn_final(
        const float* s_rel, const float* __restrict__ value_t,
        const float* __restrict__ e_src, const float* __restrict__ e_tgt,
        const int* __restrict__ adj, const unsigned char* __restrict__ mask,
        const float* __restrict__ Wf, const float* __restrict__ bias,
        const float* __restrict__ inp,
        float* __restrict__ out_av, float* out_ar, float* __restrict__ outf) {
    __shared__ float xls[4][1024];   // 16 KB: per row, [xv(512) | xr(512)]
    __shared__ float ltmp[2048];     // 8 KB: phase1 = lav/lar (256 f/wave); phase2 = psum[4][512]
    const int t = threadIdx.x;       // 0..511
    const int lane = t & 63;
    const int w = t >> 6;            // 0..7
    const int r = w >> 1;            // row-in-quad
    const int hh = w & 1;            // head half
    const int b = blockIdx.x >> 5;   // 0..7
    const int iq = blockIdx.x & 31;
    const int i = iq * 4 + r;
    const int j0 = lane, j1 = lane + 64;
    float* lav = &ltmp[w * 256];     // wave-private, no barrier needed
    float* lar = lav + 128;

    const unsigned char m0 = mask[(size_t)(b * 128 + i) * 128 + j0];
    const unsigned char m1 = mask[(size_t)(b * 128 + i) * 128 + j1];

    for (int h8 = 0; h8 < 4; h8++) {
        const int h = hh * 4 + h8;
        const int bh = b * 8 + h;
        const size_t rowbase = ((size_t)bh * 128 + i) * 128;
        const float etg = e_tgt[bh * 128 + i];

        float sv0 = leaky(etg + e_src[bh * 128 + j0]);
        float sv1 = leaky(etg + e_src[bh * 128 + j1]);
        float sr0 = s_rel[rowbase + j0];
        float sr1 = s_rel[rowbase + j1];
        int a0 = adj[rowbase + j0], a1 = adj[rowbase + j1];
        bool bad0 = m0 || (a0 == 0);
        bool bad1 = m1 || (a1 == 0);
        if (bad0) { sv0 = -1e30f; sr0 = -1e30f; }
        if (bad1) { sv1 = -1e30f; sr1 = -1e30f; }

        float mv = fmaxf(sv0, sv1), mr = fmaxf(sr0, sr1);
#pragma unroll
        for (int off = 32; off >= 1; off >>= 1) {
            mv = fmaxf(mv, __shfl_xor(mv, off, 64));
            mr = fmaxf(mr, __shfl_xor(mr, off, 64));
        }
        float pv0 = bad0 ? 0.f : __expf(sv0 - mv);
        float pv1 = bad1 ? 0.f : __expf(sv1 - mv);
        float pr0 = bad0 ? 0.f : __expf(sr0 - mr);
        float pr1 = bad1 ? 0.f : __expf(sr1 - mr);
        float sumv = pv0 + pv1, sumr = pr0 + pr1;
#pragma unroll
        for (int off = 32; off >= 1; off >>= 1) {
            sumv += __shfl_xor(sumv, off, 64);
            sumr += __shfl_xor(sumr, off, 64);
        }
        float iv = 1.f / fmaxf(sumv, 1e-12f);
        float ir = 1.f / fmaxf(sumr, 1e-12f);
        float av0 = pv0 * iv, av1 = pv1 * iv;
        float ar0 = pr0 * ir, ar1 = pr1 * ir;

        out_av[rowbase + j0] = av0;
        out_av[rowbase + j1] = av1;
        out_ar[rowbase + j0] = ar0;
        out_ar[rowbase + j1] = ar1;

        // wave-private LDS slice; written+read by wave w only (no barrier)
        lav[j0] = av0; lav[j1] = av1;
        lar[j0] = ar0; lar[j1] = ar1;

        const float4* vrow = (const float4*)(value_t + ((size_t)bh * 64 + lane) * 128);
        float accv = 0.f, accr = 0.f;
#pragma unroll 8
        for (int jb = 0; jb < 32; jb++) {
            float4 v4 = vrow[jb];
            float4 a4 = *(const float4*)&lav[jb * 4];
            float4 r4 = *(const float4*)&lar[jb * 4];
            accv = fmaf(a4.x, v4.x, accv); accv = fmaf(a4.y, v4.y, accv);
            accv = fmaf(a4.z, v4.z, accv); accv = fmaf(a4.w, v4.w, accv);
            accr = fmaf(r4.x, v4.x, accr); accr = fmaf(r4.y, v4.y, accr);
            accr = fmaf(r4.z, v4.z, accr); accr = fmaf(r4.w, v4.w, accr);
        }
        xls[r][h * 64 + lane] = accv;
        xls[r][512 + h * 64 + lane] = accr;
    }
    __syncthreads();   // xls complete; lav/lar dead -> ltmp reusable as psum

    // ---- final GEMM, split-K: group g covers K [g*512, g*512+512) ----
    const int g  = t >> 8;           // 0 or 1
    const int tt = t & 255;
    const int c0 = tt * 2;
    const int kb = g * 512;
    float acc[4][2] = {};
    for (int k0 = 0; k0 < 512; k0 += 4) {
        float4 xr[4];
#pragma unroll
        for (int rr = 0; rr < 4; rr++) xr[rr] = *(const float4*)&xls[rr][kb + k0];
#define FSTEP(COMP, I)                                                          \
        {                                                                       \
            float2 wv = *(const float2*)(Wf + (size_t)(kb + k0 + I) * 512 + c0);\
            _Pragma("unroll")                                                   \
            for (int rr = 0; rr < 4; rr++) {                                    \
                acc[rr][0] = fmaf(xr[rr].COMP, wv.x, acc[rr][0]);               \
                acc[rr][1] = fmaf(xr[rr].COMP, wv.y, acc[rr][1]);               \
            }                                                                   \
        }
        FSTEP(x, 0) FSTEP(y, 1) FSTEP(z, 2) FSTEP(w, 3)
#undef FSTEP
    }
    if (g == 1) {
#pragma unroll
        for (int rr = 0; rr < 4; rr++)
            *(float2*)&ltmp[rr * 512 + c0] = make_float2(acc[rr][0], acc[rr][1]);
    }
    __syncthreads();
    if (g == 0) {
        const int row0 = blockIdx.x * 4;
        float b0 = bias[c0], b1 = bias[c0 + 1];
#pragma unroll
        for (int rr = 0; rr < 4; rr++) {
            size_t ro = (size_t)(row0 + rr) * 512;
            float2 p   = *(const float2*)&ltmp[rr * 512 + c0];
            float2 ivl = *(const float2*)(inp + ro + c0);
            float v0 = acc[rr][0] + p.x + b0 + ivl.x;
            float v1 = acc[rr][1] + p.y + b1 + ivl.y;
            *(float2*)&outf[ro + c0] = make_float2(v0, v1);
        }
    }
}

// ---------------------------------------------------------------------------
extern "C" void kernel_launch(void* const* d_in, const int* in_sizes, int n_in,
                              void* d_out, int out_size, void* d_ws, size_t ws_size,
                              hipStream_t stream) {
    const float* inp  = (const float*)d_in[0];
    const float* rel  = (const float*)d_in[1];
    const unsigned char* mask = (const unsigned char*)d_in[2];
    const int*   adj  = (const int*)d_in[3];
    const float* Wv   = (const float*)d_in[7];
    const float* Wr   = (const float*)d_in[8];
    const float* wsrc = (const float*)d_in[9];
    const float* wtgt = (const float*)d_in[10];
    const float* wrel = (const float*)d_in[11];
    const float* Wf   = (const float*)d_in[12];
    const float* bfin = (const float*)d_in[13];

    float* outf   = (float*)d_out;
    float* out_av = outf + (size_t)B_ * L_ * D_;                 // +524288
    float* out_ar = out_av + (size_t)B_ * H_ * L_ * L_;          // +1048576

    char* ws = (char*)d_ws;
    float* wr_eff  = (float*)(ws);                       // 16 KB
    float* value_t = (float*)(ws + 16384);               // 2 MB
    float* e_src   = (float*)(ws + 2113536);             // 32 KB
    float* e_tgt   = (float*)(ws + 2146304);             // 32 KB (ends ~2.1 MB)

    k_wreff<<<16, 256, 0, stream>>>(Wr, wrel, wr_eff);
    k_srel_value<<<2304, 256, 0, stream>>>(rel, wr_eff, inp, Wv, wsrc, wtgt,
                                           out_ar, value_t, e_src, e_tgt);
    k_attn_final<<<256, 512, 0, stream>>>(out_ar, value_t, e_src, e_tgt, adj, mask,
                                          Wf, bfin, inp, out_av, out_ar, outf);
}